// Round 8
// baseline (289.504 us; speedup 1.0000x reference)
//
#include <hip/hip_runtime.h>
#include <hip/hip_bf16.h>
#include <cmath>

typedef __attribute__((ext_vector_type(8))) short short8;
typedef __attribute__((ext_vector_type(16))) short short16;
typedef __attribute__((ext_vector_type(4))) short s16x4;
typedef __attribute__((ext_vector_type(4))) float f32x4;
typedef __attribute__((ext_vector_type(2))) float f32x2;
typedef unsigned short u16;

#define HW 9216   // 96*96

__device__ inline float bf2f(u16 u) {
    union { unsigned int i; float f; } x; x.i = ((unsigned int)u) << 16; return x.f;
}
__device__ inline u16 f2bf(float f) {
    union { unsigned int i; float f; } x; x.f = f;
    unsigned int r = x.i + 0x7FFF + ((x.i >> 16) & 1);
    return (u16)(r >> 16);
}

// Direct global->LDS DMA, 16 B per lane. LDS dest = wave-uniform base + lane*16;
// global src is per-lane (carries the gather/zero-fill redirect).
__device__ inline void gload16(const u16* g, u16* l) {
    __builtin_amdgcn_global_load_lds(
        (const __attribute__((address_space(1))) void*)g,
        (__attribute__((address_space(3))) void*)l,
        16, 0, 0);
}

// ---------------------------------------------------------------------------
// Weight transform (fp32 -> bf16):
//   w_red [128,256,3,3] -> Wt1 [128][2304], k = c*288 + khw*32 + ciL  (ci-chunk major!)
//   w_la2 [128,16,3,3]  -> Wt2 [128][160],  k = khw*16 + ci, zero pad 144..159
//   (Wt2's zero tail doubles as the 16B zero-page for conv halo lanes.)
// ---------------------------------------------------------------------------
__global__ __launch_bounds__(256) void transform_w(
    const float* __restrict__ wred, const float* __restrict__ wla2,
    u16* __restrict__ Wt1, u16* __restrict__ Wt2)
{
    int idx = blockIdx.x * 256 + threadIdx.x;
    if (idx < 128 * 2304) {
        int co = idx / 2304;
        int rem = idx - co * 2304;
        int c = rem / 288;
        int r2 = rem - c * 288;
        int khw = r2 >> 5, ciL = r2 & 31;
        Wt1[idx] = f2bf(wred[((co * 256 + c * 32 + ciL) * 9 + khw)]);
    } else {
        int i2 = idx - 128 * 2304;
        if (i2 < 128 * 160) {
            int co = i2 / 160;
            int k = i2 - co * 160;
            int khw = k >> 4, ci = k & 15;
            Wt2[i2] = (khw < 9) ? f2bf(wla2[((co << 4) + ci) * 9 + khw]) : (u16)0;
        }
    }
}

// ---------------------------------------------------------------------------
// x [b][ci][p] fp32 -> xt [b][p][ci] bf16 (NHWC).
// Grid 2304 = 8 batch x 36 px-chunks x 8 ch-groups -> exactly 9 blocks/CU.
// Each thread: 1 pixel, 32 ch, two 32B stores (short16).
// ---------------------------------------------------------------------------
__global__ __launch_bounds__(256) void transpose_x(
    const float* __restrict__ X, u16* __restrict__ Xt)
{
    int bid = blockIdx.x;
    int b = bid & 7;
    int rem = bid >> 3;             // 0..287
    int chunk = rem % 36;           // 256-px chunk
    int q = rem / 36;               // ch-group 0..7 (32 channels each)
    int p = chunk * 256 + threadIdx.x;
    const float* xb = X + (size_t)b * 256 * HW + p;
    u16* ot = Xt + ((size_t)b * HW + p) * 256;
#pragma unroll
    for (int o2 = 0; o2 < 2; ++o2) {
        int c0 = q * 32 + o2 * 16;
        short16 v;
#pragma unroll
        for (int j = 0; j < 16; ++j)
            v[j] = (short)f2bf(xb[(size_t)(c0 + j) * HW]);
        *(short16*)(ot + c0) = v;   // 32B store, 32B-aligned
    }
}

// ---------------------------------------------------------------------------
// Implicit-GEMM 3x3 SAME conv via MFMA 16x16x32 bf16, NHWC bf16 input.
// R4 structure (proven fastest: 73.9 µs): all staging via global_load_lds w16,
// double-buffered LDS, depth-1 prefetch, one __syncthreads()/iter.
// C[co(128)][px(96=32w x 3h)]; grid 768 = 3 blocks/CU. Waves 2m x 2n,
// each 64co x 48px (acc 4x3). T5 setprio around the MFMA cluster.
// EPI==1: BN+SiLU -> bf16 OutH (xr).  EPI==2: out = xr + ctx*(1+tanh) -> fp32.
// ---------------------------------------------------------------------------
template<int CIN, int KTILES, int KP, int EPI>
__global__ __launch_bounds__(256) void conv_k(
    const u16* __restrict__ Xt, const u16* __restrict__ Wt,
    u16* OutH, float* OutF,
    const float* __restrict__ bg, const float* __restrict__ bb,
    const float* __restrict__ bm, const float* __restrict__ bv,
    const u16* __restrict__ xrb, const float* ctxf,
    const u16* __restrict__ zp)
{
    __shared__ __align__(16) short As[2][128 * 32];   // 16 KB
    __shared__ __align__(16) short Bs[2][96 * 32];    // 12 KB
    __shared__ float invA[128], betA[128];

    const int tid = threadIdx.x;
    const int bid = blockIdx.x;
    const int b = bid & 7;
    const int tile = bid >> 3;            // [0,96)
    const int w0 = (tile % 3) * 32;
    const int h0 = (tile / 3) * 3;        // 3-row tiles

    const int lane = tid & 63;
    const int wid = tid >> 6;
    const int wm = (wid & 1) * 64;   // m (co) offset of this wave
    const int wn = (wid >> 1) * 48;  // n (pixel) offset
    const int r = lane & 15;
    const int quad = lane >> 4;

    if constexpr (EPI == 1) {
        if (tid < 128) {
            float iv = bg[tid] * rsqrtf(bv[tid] + 1e-5f);
            invA[tid] = iv;
            betA[tid] = bb[tid] - bm[tid] * iv;
        }
    }

    const u16* XtB = Xt + (size_t)b * HW * CIN;

    // 16B slots: A = [128 rows][4 slots] (512), B = [96 rows][4 slots] (384).
    // Thread t covers A-slots {t, t+256}; B-slot t; B-slot t+256 for wid<2.
    // Wave w's lanes are slots [64w, 64w+64) of each batch -> LDS base uniform.
    auto bsrc = [&](int slot, int kt) -> const u16* {
        int row = slot >> 2, o = slot & 3;
        int pw = row & 31, ph = row >> 5;        // 32w x 3h
        int hgl = h0 + ph, wgl = w0 + pw;
        if (CIN == 256) {
            int c = (kt * 57) >> 9;              // kt/9
            int khw = kt - c * 9;
            int dh = (khw * 11) >> 5;            // khw/3
            int dw = khw - 3 * dh;
            int hh = hgl + dh - 1, ww = wgl + dw - 1;
            bool ok = ((unsigned)hh < 96u) && ((unsigned)ww < 96u);
            return ok ? XtB + ((size_t)hh * 96 + ww) * 256 + c * 32 + o * 8 : zp;
        } else {
            int kg = kt * 32 + o * 8;
            int khw = kg >> 4, ci0 = kg & 15;
            int dh = (khw * 11) >> 5, dw = khw - 3 * dh;
            int hh = hgl + dh - 1, ww = wgl + dw - 1;
            bool ok = ((unsigned)hh < 96u) && ((unsigned)ww < 96u) && (khw < 9);
            return ok ? XtB + ((size_t)hh * 96 + ww) * 16 + ci0 : zp;
        }
    };

    auto stage = [&](int kt, int buf) {
        int sA0 = tid, sA1 = tid + 256;
        gload16(Wt + (size_t)(sA0 >> 2) * KP + kt * 32 + (sA0 & 3) * 8,
                (u16*)&As[buf][(64 * wid) * 8]);
        gload16(Wt + (size_t)(sA1 >> 2) * KP + kt * 32 + (sA1 & 3) * 8,
                (u16*)&As[buf][(256 + 64 * wid) * 8]);
        gload16(bsrc(tid, kt), (u16*)&Bs[buf][(64 * wid) * 8]);
        if (wid < 2)
            gload16(bsrc(tid + 256, kt), (u16*)&Bs[buf][(256 + 64 * wid) * 8]);
    };

    f32x4 acc[4][3];
    f32x4 zz = {0.f, 0.f, 0.f, 0.f};
#pragma unroll
    for (int i = 0; i < 4; i++)
#pragma unroll
        for (int j = 0; j < 3; j++) acc[i][j] = zz;

    // prologue
    stage(0, 0);
    __syncthreads();                      // drains vmcnt -> buf0 valid

    for (int kt = 0; kt < KTILES; ++kt) {
        int cur = kt & 1;
        if (kt + 1 < KTILES) stage(kt + 1, cur ^ 1);   // loads in flight
        short8 af[4], bfr[3];
#pragma unroll
        for (int i = 0; i < 4; i++)
            af[i] = *(const short8*)(&As[cur][(wm + i * 16 + r) * 32 + quad * 8]);
#pragma unroll
        for (int j = 0; j < 3; j++)
            bfr[j] = *(const short8*)(&Bs[cur][(wn + j * 16 + r) * 32 + quad * 8]);
        __builtin_amdgcn_s_setprio(1);
#pragma unroll
        for (int i = 0; i < 4; i++)
#pragma unroll
            for (int j = 0; j < 3; j++)
                acc[i][j] = __builtin_amdgcn_mfma_f32_16x16x32_bf16(af[i], bfr[j], acc[i][j], 0, 0, 0);
        __builtin_amdgcn_s_setprio(0);
        if (kt + 1 < KTILES)
            __syncthreads();              // drains vmcnt: buf cur^1 ready; reads of cur done
    }

    // ---- epilogue (HW-verified decode): co = wm+i*16+quad*4+g ; pixel = wn+j*16+r
#pragma unroll
    for (int i = 0; i < 4; i++) {
#pragma unroll
        for (int j = 0; j < 3; j++) {
            int pl = wn + j * 16 + r;
            int w = w0 + (pl & 31), h = h0 + (pl >> 5);
#pragma unroll
            for (int g = 0; g < 4; ++g) {
                int co = wm + i * 16 + quad * 4 + g;
                float v = acc[i][j][g];
                size_t oidx = ((size_t)b * 128 + co) * HW + h * 96 + w;
                if constexpr (EPI == 1) {
                    float val = v * invA[co] + betA[co];
                    float sv = val / (1.f + __expf(-val));   // SiLU
                    OutH[oidx] = f2bf(sv);
                } else {
                    float xv = bf2f(xrb[oidx]);
                    float cv = ctxf[oidx];                   // fp32 ctx, same slot
                    float e = __expf(2.f * v);
                    float th = 1.f - 2.f / (e + 1.f);        // tanh
                    OutF[oidx] = xv + cv * (1.f + th);       // fp32 final output
                }
            }
        }
    }
}

// ---------------------------------------------------------------------------
// Per-(batch, token) prep: token = 16x16 mean of xr -> k -> V row, folded A row,
// c0. Grid 64 (b = bid&7, n = bid>>3), 256 threads.
// ---------------------------------------------------------------------------
__global__ __launch_bounds__(256) void prep_attn(
    const u16* __restrict__ xr,
    const float* __restrict__ wk, const float* __restrict__ bk,
    const float* __restrict__ wv, const float* __restrict__ bv,
    const float* __restrict__ wq, const float* __restrict__ bq,
    float* __restrict__ Aout, float* __restrict__ Vout, float* __restrict__ c0out)
{
    __shared__ float part[256];
    __shared__ float tok[128];
    __shared__ float ks[32];
    int t = threadIdx.x;
    int bid = blockIdx.x;
    int b = bid & 7, n = bid >> 3;
    int c = t & 127, half = t >> 7;
    int i0 = (n < 6) ? 0 : 16;
    int j0 = ((n < 6) ? n : (n - 6)) * 16;
    const u16* xb = xr + (size_t)(b * 128 + c) * HW;

    float s = 0.f;
    for (int rr = 0; rr < 8; ++rr) {
        int row = i0 + half * 8 + rr;
        const u16* rp = xb + row * 96 + j0;
        short8 v0 = *(const short8*)rp;
        short8 v1 = *(const short8*)(rp + 8);
#pragma unroll
        for (int j = 0; j < 8; ++j) s += bf2f((u16)v0[j]) + bf2f((u16)v1[j]);
    }
    part[t] = s;
    __syncthreads();
    if (t < 128) tok[t] = (part[t] + part[t + 128]) * (1.f / 256.f);
    __syncthreads();
    if (t < 32) {
        float s2 = bk[t];
        for (int cc = 0; cc < 128; ++cc) s2 += wk[t * 128 + cc] * tok[cc];
        ks[t] = s2;
    }
    __syncthreads();
    if (t < 128) {
        float s3 = bv[c];
        for (int c2 = 0; c2 < 128; ++c2) s3 += wv[c * 128 + c2] * tok[c2];
        Vout[((size_t)b * 8 + n) * 128 + c] = s3;
    } else {
        float s4 = 0.f;
        for (int d = 0; d < 32; ++d) s4 += wq[d * 128 + c] * ks[d];
        Aout[((size_t)b * 8 + n) * 128 + c] = s4;
    }
    if (t == 0) {
        float s5 = 0.f;
        for (int d = 0; d < 32; ++d) s5 += bq[d] * ks[d];
        c0out[b * 8 + n] = s5;
    }
}

// ---------------------------------------------------------------------------
// Fused attention + LocalAtten 1x1 branch. 64 px/block, grid 1152 1-D
// (b = bid&7). ctx -> fp32 d_out; y -> NHWC-16 bf16 (for conv2 staging).
// R8: A/V/W1 stored TRANSPOSED in LDS ([c][n] / [c][n] / [c][d]) so the
// per-c wave-uniform operand reads become ONE b64/b128 instead of 2-8 scalar
// b32s. Per-wave ds-instr count ~1400 -> ~700 (LDS issue port was the bound:
// every uniform ds_read_b32 = 5.8cy for one scalar). Xs staging writes packed
// to b128. All arithmetic fp32, bit-pattern identical math.
// ---------------------------------------------------------------------------
__global__ __launch_bounds__(256) void attn_k(
    const u16* __restrict__ xr,
    const float* __restrict__ Ain, const float* __restrict__ Vin,
    const float* __restrict__ c0in,
    const float* __restrict__ wla1,
    const float* __restrict__ lag, const float* __restrict__ lab,
    const float* __restrict__ lam, const float* __restrict__ lav,
    float* __restrict__ ctxout, u16* __restrict__ yout)
{
    __shared__ __align__(16) float Xs[128 * 64];     // xr tile, later reused for ctx
    __shared__ __align__(16) float Ast[128 * 8];     // [c][n]
    __shared__ __align__(16) float Vst[128 * 8];     // [c][n]
    __shared__ __align__(16) float Wst[128 * 16];    // [c][d]
    __shared__ float satt[8 * 64];
    __shared__ float c0s[8], inv1[16], bet1[16];

    int t = threadIdx.x;
    int bid = blockIdx.x;
    int b = bid & 7;
    int p0 = (bid >> 3) * 64;

    for (int i = t; i < 1024; i += 256) {
        int n = i >> 7, c = i & 127;
        Ast[c * 8 + n] = Ain[b * 1024 + i];
        Vst[c * 8 + n] = Vin[b * 1024 + i];
    }
    for (int i = t; i < 2048; i += 256) {
        int d = i >> 7, c = i & 127;
        Wst[c * 16 + d] = wla1[i];
    }
    if (t < 8) c0s[t] = c0in[b * 8 + t];
    if (t < 16) {
        float iv = lag[t] * rsqrtf(lav[t] + 1e-5f);
        inv1[t] = iv; bet1[t] = lab[t] - lam[t] * iv;
    }
    const u16* xb = xr + (size_t)b * 128 * HW + p0;
#pragma unroll
    for (int it = 0; it < 4; ++it) {
        int c = (t >> 3) + it * 32;
        int seg = t & 7;
        short8 v = *(const short8*)(xb + (size_t)c * HW + seg * 8);
        f32x4 f0, f1;
#pragma unroll
        for (int j = 0; j < 4; ++j) { f0[j] = bf2f((u16)v[j]); f1[j] = bf2f((u16)v[j + 4]); }
        *(f32x4*)(&Xs[c * 64 + seg * 8]) = f0;       // packed b128 LDS writes
        *(f32x4*)(&Xs[c * 64 + seg * 8 + 4]) = f1;
    }
    __syncthreads();
    {
        int pp = t & 63, ng = t >> 6;
        float a0 = 0.f, a1 = 0.f;
        for (int c = 0; c < 128; ++c) {
            float x = Xs[c * 64 + pp];
            f32x2 av = *(const f32x2*)(&Ast[c * 8 + ng * 2]);   // 1 uniform b64 (both n)
            a0 += av[0] * x;
            a1 += av[1] * x;
        }
        satt[(ng * 2) * 64 + pp] = a0 + c0s[ng * 2];
        satt[(ng * 2 + 1) * 64 + pp] = a1 + c0s[ng * 2 + 1];
    }
    __syncthreads();
    if (t < 64) {
        float m = -1e30f;
        float sv[8];
#pragma unroll
        for (int n = 0; n < 8; ++n) { sv[n] = satt[n * 64 + t]; m = fmaxf(m, sv[n]); }
        float sum = 0.f;
#pragma unroll
        for (int n = 0; n < 8; ++n) { sv[n] = __expf(sv[n] - m); sum += sv[n]; }
        float rcp = 1.f / sum;
#pragma unroll
        for (int n = 0; n < 8; ++n) satt[n * 64 + t] = sv[n] * rcp;
    }
    __syncthreads();
    {
        int pp = t & 63, cg = t >> 6;
        float at[8];
#pragma unroll
        for (int n = 0; n < 8; ++n) at[n] = satt[n * 64 + pp];
        for (int ci = 0; ci < 32; ++ci) {
            int c = cg * 32 + ci;
            f32x4 v0 = *(const f32x4*)(&Vst[c * 8]);       // 2 uniform b128 (8 n)
            f32x4 v1 = *(const f32x4*)(&Vst[c * 8 + 4]);
            float s = at[0] * v0[0] + at[1] * v0[1] + at[2] * v0[2] + at[3] * v0[3]
                    + at[4] * v1[0] + at[5] * v1[1] + at[6] * v1[2] + at[7] * v1[3];
            ctxout[((size_t)b * 128 + c) * HW + p0 + pp] = s;   // fp32
            Xs[c * 64 + pp] = s;
        }
    }
    __syncthreads();
    {
        int pp = t & 63, dg = t >> 6;
        float a[4] = {0.f, 0.f, 0.f, 0.f};
        for (int c = 0; c < 128; ++c) {
            float x = Xs[c * 64 + pp];
            f32x4 w = *(const f32x4*)(&Wst[c * 16 + dg * 4]);  // 1 uniform b128 (4 d)
#pragma unroll
            for (int k = 0; k < 4; ++k) a[k] += w[k] * x;
        }
        s16x4 pk;
#pragma unroll
        for (int k = 0; k < 4; ++k) {
            int d = dg * 4 + k;
            float val = a[k] * inv1[d] + bet1[d];
            float s = val / (1.f + __expf(-val));
            pk[k] = (short)f2bf(s);
        }
        // y in NHWC-16: yt[b][p][d]
        *(s16x4*)(yout + ((size_t)b * HW + p0 + pp) * 16 + dg * 4) = pk;
    }
}

// ---------------------------------------------------------------------------
extern "C" void kernel_launch(void* const* d_in, const int* in_sizes, int n_in,
                              void* d_out, int out_size, void* d_ws, size_t ws_size,
                              hipStream_t stream)
{
    const float* x    = (const float*)d_in[0];
    const float* wred = (const float*)d_in[1];
    const float* bng  = (const float*)d_in[2];
    const float* bnb  = (const float*)d_in[3];
    const float* bnm  = (const float*)d_in[4];
    const float* bnv  = (const float*)d_in[5];
    const float* wq   = (const float*)d_in[6];
    const float* bq   = (const float*)d_in[7];
    const float* wk   = (const float*)d_in[8];
    const float* bk   = (const float*)d_in[9];
    const float* wv   = (const float*)d_in[10];
    const float* bv   = (const float*)d_in[11];
    // d_in[12] = lsh: provably unused (permutation-invariance of softmax attention)
    const float* wla1 = (const float*)d_in[13];
    const float* lag  = (const float*)d_in[14];
    const float* lab  = (const float*)d_in[15];
    const float* lam  = (const float*)d_in[16];
    const float* lav  = (const float*)d_in[17];
    const float* wla2 = (const float*)d_in[18];

    char* ws = (char*)d_ws;
    u16*   xr  = (u16*)(ws + 0);            // 18,874,368 B  bf16 CHW
    u16*   yt  = (u16*)(ws + 18874368);     //  2,359,296 B  bf16 NHWC-16
    u16*   Wt1 = (u16*)(ws + 21233664);     //    589,824 B
    u16*   Wt2 = (u16*)(ws + 21823488);     //     40,960 B
    float* Ab  = (float*)(ws + 21864448);   //     32,768 B
    float* Vb  = (float*)(ws + 21897216);   //     32,768 B
    float* c0b = (float*)(ws + 21929984);   //        256 B
    // xt (NHWC-256 bf16, 37,748,736 B) lives in d_out until attn_k overwrites
    // it with fp32 ctx — conv1/prep complete before that (stream-ordered).
    u16*   xt   = (u16*)d_out;
    float* outp = (float*)d_out;
    // 16B zero region for conv halo lanes: Wt2's zero-padded tail (co=0,
    // k=144..151), written to 0 by transform_w each launch, 16B-aligned.
    const u16* zp = Wt2 + 144;

    transform_w<<<dim3(1232), dim3(256), 0, stream>>>(wred, wla2, Wt1, Wt2);

    transpose_x<<<dim3(2304), dim3(256), 0, stream>>>(x, xt);

    conv_k<256, 72, 2304, 1><<<dim3(768), dim3(256), 0, stream>>>(
        xt, Wt1, xr, nullptr, bng, bnb, bnm, bnv, nullptr, nullptr, zp);

    prep_attn<<<dim3(64), dim3(256), 0, stream>>>(xr, wk, bk, wv, bv, wq, bq, Ab, Vb, c0b);

    attn_k<<<dim3(1152), dim3(256), 0, stream>>>(
        xr, Ab, Vb, c0b, wla1, lag, lab, lam, lav, outp, yt);

    conv_k<16, 5, 160, 2><<<dim3(768), dim3(256), 0, stream>>>(
        yt, Wt2, nullptr, outp, nullptr, nullptr, nullptr, nullptr, xr, outp, zp);
}

// Round 9
// 279.205 us; speedup vs baseline: 1.0369x; 1.0369x over previous
//
#include <hip/hip_runtime.h>
#include <hip/hip_bf16.h>
#include <cmath>

typedef __attribute__((ext_vector_type(8))) short short8;
typedef __attribute__((ext_vector_type(16))) short short16;
typedef __attribute__((ext_vector_type(4))) short s16x4;
typedef __attribute__((ext_vector_type(4))) float f32x4;
typedef __attribute__((ext_vector_type(2))) float f32x2;
typedef unsigned short u16;

#define HW 9216   // 96*96

__device__ inline float bf2f(u16 u) {
    union { unsigned int i; float f; } x; x.i = ((unsigned int)u) << 16; return x.f;
}
__device__ inline u16 f2bf(float f) {
    union { unsigned int i; float f; } x; x.f = f;
    unsigned int r = x.i + 0x7FFF + ((x.i >> 16) & 1);
    return (u16)(r >> 16);
}

// Direct global->LDS DMA, 16 B per lane. LDS dest = wave-uniform base + lane*16;
// global src is per-lane (carries the gather/zero-fill redirect).
__device__ inline void gload16(const u16* g, u16* l) {
    __builtin_amdgcn_global_load_lds(
        (const __attribute__((address_space(1))) void*)g,
        (__attribute__((address_space(3))) void*)l,
        16, 0, 0);
}

// ---------------------------------------------------------------------------
// Weight transform (fp32 -> bf16):
//   w_red [128,256,3,3] -> Wt1 [128][2304], k = c*288 + khw*32 + ciL  (ci-chunk major!)
//   w_la2 [128,16,3,3]  -> Wt2 [128][160],  k = khw*16 + ci, zero pad 144..159
//   (Wt2's zero tail doubles as the 16B zero-page for conv halo lanes.)
// ---------------------------------------------------------------------------
__global__ __launch_bounds__(256) void transform_w(
    const float* __restrict__ wred, const float* __restrict__ wla2,
    u16* __restrict__ Wt1, u16* __restrict__ Wt2)
{
    int idx = blockIdx.x * 256 + threadIdx.x;
    if (idx < 128 * 2304) {
        int co = idx / 2304;
        int rem = idx - co * 2304;
        int c = rem / 288;
        int r2 = rem - c * 288;
        int khw = r2 >> 5, ciL = r2 & 31;
        Wt1[idx] = f2bf(wred[((co * 256 + c * 32 + ciL) * 9 + khw)]);
    } else {
        int i2 = idx - 128 * 2304;
        if (i2 < 128 * 160) {
            int co = i2 / 160;
            int k = i2 - co * 160;
            int khw = k >> 4, ci = k & 15;
            Wt2[i2] = (khw < 9) ? f2bf(wla2[((co << 4) + ci) * 9 + khw]) : (u16)0;
        }
    }
}

// ---------------------------------------------------------------------------
// x [b][ci][p] fp32 -> xt [b][p][ci] bf16 (NHWC).
// R9: LDS-tiled. Block = 64 px x 256 c; grid 1152 (b = bid&7). Reads stay
// coalesced (lanes along p); writes become 512B-contiguous per 4 lanes
// (was 32B chunks at 512B stride -> write amplification).
// ---------------------------------------------------------------------------
__global__ __launch_bounds__(256) void transpose_x(
    const float* __restrict__ X, u16* __restrict__ Xt)
{
    __shared__ u16 Lt[256][66];          // [c][p], +2 pad
    int t = threadIdx.x;
    int bid = blockIdx.x;
    int b = bid & 7;
    int p0 = (bid >> 3) * 64;            // 144 chunks of 64 px
    int pp = t & 63, c4 = t >> 6;        // wave w handles c = r*4 + w
    const float* xb = X + (size_t)b * 256 * HW + p0 + pp;
    for (int r = 0; r < 64; ++r) {
        int c = r * 4 + c4;
        Lt[c][pp] = f2bf(xb[(size_t)c * HW]);
    }
    __syncthreads();
    int p = t >> 2, cq = t & 3;          // 4 lanes cover one 512B px row
    u16* ot = Xt + ((size_t)b * HW + p0 + p) * 256 + cq * 64;
#pragma unroll
    for (int o = 0; o < 4; ++o) {
        short16 v;
#pragma unroll
        for (int j = 0; j < 16; ++j)
            v[j] = (short)Lt[cq * 64 + o * 16 + j][p];
        *(short16*)(ot + o * 16) = v;    // 32B store; 4 lanes = contiguous 512B
    }
}

// ---------------------------------------------------------------------------
// Implicit-GEMM 3x3 SAME conv via MFMA 16x16x32 bf16, NHWC bf16 input.
// R4 structure (proven fastest): all staging via global_load_lds w16,
// double-buffered LDS, depth-1 prefetch, one __syncthreads()/iter.
// C[co(128)][px(96=32w x 3h)]; grid 768 = 3 blocks/CU. Waves 2m x 2n,
// each 64co x 48px (acc 4x3). T5 setprio around the MFMA cluster.
// EPI==1: BN+SiLU -> bf16 OutH (xr).  EPI==2: out = xr + ctx*(1+tanh) -> fp32.
// ---------------------------------------------------------------------------
template<int CIN, int KTILES, int KP, int EPI>
__global__ __launch_bounds__(256) void conv_k(
    const u16* __restrict__ Xt, const u16* __restrict__ Wt,
    u16* OutH, float* OutF,
    const float* __restrict__ bg, const float* __restrict__ bb,
    const float* __restrict__ bm, const float* __restrict__ bv,
    const u16* __restrict__ xrb, const float* ctxf,
    const u16* __restrict__ zp)
{
    __shared__ __align__(16) short As[2][128 * 32];   // 16 KB
    __shared__ __align__(16) short Bs[2][96 * 32];    // 12 KB
    __shared__ float invA[128], betA[128];

    const int tid = threadIdx.x;
    const int bid = blockIdx.x;
    const int b = bid & 7;
    const int tile = bid >> 3;            // [0,96)
    const int w0 = (tile % 3) * 32;
    const int h0 = (tile / 3) * 3;        // 3-row tiles

    const int lane = tid & 63;
    const int wid = tid >> 6;
    const int wm = (wid & 1) * 64;   // m (co) offset of this wave
    const int wn = (wid >> 1) * 48;  // n (pixel) offset
    const int r = lane & 15;
    const int quad = lane >> 4;

    if constexpr (EPI == 1) {
        if (tid < 128) {
            float iv = bg[tid] * rsqrtf(bv[tid] + 1e-5f);
            invA[tid] = iv;
            betA[tid] = bb[tid] - bm[tid] * iv;
        }
    }

    const u16* XtB = Xt + (size_t)b * HW * CIN;

    // 16B slots: A = [128 rows][4 slots] (512), B = [96 rows][4 slots] (384).
    // Thread t covers A-slots {t, t+256}; B-slot t; B-slot t+256 for wid<2.
    // Wave w's lanes are slots [64w, 64w+64) of each batch -> LDS base uniform.
    auto bsrc = [&](int slot, int kt) -> const u16* {
        int row = slot >> 2, o = slot & 3;
        int pw = row & 31, ph = row >> 5;        // 32w x 3h
        int hgl = h0 + ph, wgl = w0 + pw;
        if (CIN == 256) {
            int c = (kt * 57) >> 9;              // kt/9
            int khw = kt - c * 9;
            int dh = (khw * 11) >> 5;            // khw/3
            int dw = khw - 3 * dh;
            int hh = hgl + dh - 1, ww = wgl + dw - 1;
            bool ok = ((unsigned)hh < 96u) && ((unsigned)ww < 96u);
            return ok ? XtB + ((size_t)hh * 96 + ww) * 256 + c * 32 + o * 8 : zp;
        } else {
            int kg = kt * 32 + o * 8;
            int khw = kg >> 4, ci0 = kg & 15;
            int dh = (khw * 11) >> 5, dw = khw - 3 * dh;
            int hh = hgl + dh - 1, ww = wgl + dw - 1;
            bool ok = ((unsigned)hh < 96u) && ((unsigned)ww < 96u) && (khw < 9);
            return ok ? XtB + ((size_t)hh * 96 + ww) * 16 + ci0 : zp;
        }
    };

    auto stage = [&](int kt, int buf) {
        int sA0 = tid, sA1 = tid + 256;
        gload16(Wt + (size_t)(sA0 >> 2) * KP + kt * 32 + (sA0 & 3) * 8,
                (u16*)&As[buf][(64 * wid) * 8]);
        gload16(Wt + (size_t)(sA1 >> 2) * KP + kt * 32 + (sA1 & 3) * 8,
                (u16*)&As[buf][(256 + 64 * wid) * 8]);
        gload16(bsrc(tid, kt), (u16*)&Bs[buf][(64 * wid) * 8]);
        if (wid < 2)
            gload16(bsrc(tid + 256, kt), (u16*)&Bs[buf][(256 + 64 * wid) * 8]);
    };

    f32x4 acc[4][3];
    f32x4 zz = {0.f, 0.f, 0.f, 0.f};
#pragma unroll
    for (int i = 0; i < 4; i++)
#pragma unroll
        for (int j = 0; j < 3; j++) acc[i][j] = zz;

    // prologue
    stage(0, 0);
    __syncthreads();                      // drains vmcnt -> buf0 valid

    for (int kt = 0; kt < KTILES; ++kt) {
        int cur = kt & 1;
        if (kt + 1 < KTILES) stage(kt + 1, cur ^ 1);   // loads in flight
        short8 af[4], bfr[3];
#pragma unroll
        for (int i = 0; i < 4; i++)
            af[i] = *(const short8*)(&As[cur][(wm + i * 16 + r) * 32 + quad * 8]);
#pragma unroll
        for (int j = 0; j < 3; j++)
            bfr[j] = *(const short8*)(&Bs[cur][(wn + j * 16 + r) * 32 + quad * 8]);
        __builtin_amdgcn_s_setprio(1);
#pragma unroll
        for (int i = 0; i < 4; i++)
#pragma unroll
            for (int j = 0; j < 3; j++)
                acc[i][j] = __builtin_amdgcn_mfma_f32_16x16x32_bf16(af[i], bfr[j], acc[i][j], 0, 0, 0);
        __builtin_amdgcn_s_setprio(0);
        if (kt + 1 < KTILES)
            __syncthreads();              // drains vmcnt: buf cur^1 ready; reads of cur done
    }

    // ---- epilogue (HW-verified decode): co = wm+i*16+quad*4+g ; pixel = wn+j*16+r
#pragma unroll
    for (int i = 0; i < 4; i++) {
#pragma unroll
        for (int j = 0; j < 3; j++) {
            int pl = wn + j * 16 + r;
            int w = w0 + (pl & 31), h = h0 + (pl >> 5);
#pragma unroll
            for (int g = 0; g < 4; ++g) {
                int co = wm + i * 16 + quad * 4 + g;
                float v = acc[i][j][g];
                size_t oidx = ((size_t)b * 128 + co) * HW + h * 96 + w;
                if constexpr (EPI == 1) {
                    float val = v * invA[co] + betA[co];
                    float sv = val / (1.f + __expf(-val));   // SiLU
                    OutH[oidx] = f2bf(sv);
                } else {
                    float xv = bf2f(xrb[oidx]);
                    float cv = ctxf[oidx];                   // fp32 ctx, same slot
                    float e = __expf(2.f * v);
                    float th = 1.f - 2.f / (e + 1.f);        // tanh
                    OutF[oidx] = xv + cv * (1.f + th);       // fp32 final output
                }
            }
        }
    }
}

// ---------------------------------------------------------------------------
// Per-(batch, token) prep: token = 16x16 mean of xr -> k -> V row, folded A row,
// c0, and WV row (WV = V @ W1^T, 8x16 per batch — lets attn_k compute
// y = WV @ att instead of W1 @ (V @ att): kills attn_k's 128-c y-loop).
// Grid 64 (b = bid&7, n = bid>>3), 256 threads.
// ---------------------------------------------------------------------------
__global__ __launch_bounds__(256) void prep_attn(
    const u16* __restrict__ xr,
    const float* __restrict__ wk, const float* __restrict__ bk,
    const float* __restrict__ wv, const float* __restrict__ bv,
    const float* __restrict__ wq, const float* __restrict__ bq,
    const float* __restrict__ wla1,
    float* __restrict__ Aout, float* __restrict__ Vout, float* __restrict__ c0out,
    float* __restrict__ WVout)
{
    __shared__ float part[256];
    __shared__ float tok[128];
    __shared__ float ks[32];
    __shared__ float vs[128];
    int t = threadIdx.x;
    int bid = blockIdx.x;
    int b = bid & 7, n = bid >> 3;
    int c = t & 127, half = t >> 7;
    int i0 = (n < 6) ? 0 : 16;
    int j0 = ((n < 6) ? n : (n - 6)) * 16;
    const u16* xb = xr + (size_t)(b * 128 + c) * HW;

    float s = 0.f;
    for (int rr = 0; rr < 8; ++rr) {
        int row = i0 + half * 8 + rr;
        const u16* rp = xb + row * 96 + j0;
        short8 v0 = *(const short8*)rp;
        short8 v1 = *(const short8*)(rp + 8);
#pragma unroll
        for (int j = 0; j < 8; ++j) s += bf2f((u16)v0[j]) + bf2f((u16)v1[j]);
    }
    part[t] = s;
    __syncthreads();
    if (t < 128) tok[t] = (part[t] + part[t + 128]) * (1.f / 256.f);
    __syncthreads();
    if (t < 32) {
        float s2 = bk[t];
        for (int cc = 0; cc < 128; ++cc) s2 += wk[t * 128 + cc] * tok[cc];
        ks[t] = s2;
    }
    __syncthreads();
    if (t < 128) {
        float s3 = bv[c];
        for (int c2 = 0; c2 < 128; ++c2) s3 += wv[c * 128 + c2] * tok[c2];
        Vout[((size_t)b * 8 + n) * 128 + c] = s3;
        vs[c] = s3;
    } else {
        float s4 = 0.f;
        for (int d = 0; d < 32; ++d) s4 += wq[d * 128 + c] * ks[d];
        Aout[((size_t)b * 8 + n) * 128 + c] = s4;
    }
    if (t == 0) {
        float s5 = 0.f;
        for (int d = 0; d < 32; ++d) s5 += bq[d] * ks[d];
        c0out[b * 8 + n] = s5;
    }
    __syncthreads();
    if (t < 16) {
        float s6 = 0.f;
        for (int cc = 0; cc < 128; ++cc) s6 += vs[cc] * wla1[t * 128 + cc];
        WVout[((size_t)b * 8 + n) * 16 + t] = s6;
    }
}

// ---------------------------------------------------------------------------
// Fused attention + LocalAtten 1x1 branch. 64 px/block, grid 1152 1-D
// (b = bid&7). ctx -> fp32 d_out; y -> NHWC-16 bf16 (for conv2 staging).
// R9: y computed as WV @ att (8 FMA/thread, was 128-c loop); Wst and ctx-LDS
// reuse removed; Xs kept as raw bf16 (16KB). LDS ~27KB -> 5 blocks/CU, grid
// 4.5/CU fully resident (tail gone). Math identical (fp32 reassociation only).
// ---------------------------------------------------------------------------
__global__ __launch_bounds__(256) void attn_k(
    const u16* __restrict__ xr,
    const float* __restrict__ Ain, const float* __restrict__ Vin,
    const float* __restrict__ c0in, const float* __restrict__ WVin,
    const float* __restrict__ lag, const float* __restrict__ lab,
    const float* __restrict__ lam, const float* __restrict__ lav,
    float* __restrict__ ctxout, u16* __restrict__ yout)
{
    __shared__ __align__(16) u16 Xh[128 * 64];       // xr tile, raw bf16 (16KB)
    __shared__ __align__(16) float Ast[128 * 8];     // [c][n]
    __shared__ __align__(16) float Vst[128 * 8];     // [c][n]
    __shared__ float WVs[128];                       // [n*16+d]
    __shared__ float satt[8 * 64];
    __shared__ float c0s[8], inv1[16], bet1[16];

    int t = threadIdx.x;
    int bid = blockIdx.x;
    int b = bid & 7;
    int p0 = (bid >> 3) * 64;

    for (int i = t; i < 1024; i += 256) {
        int n = i >> 7, c = i & 127;
        Ast[c * 8 + n] = Ain[b * 1024 + i];
        Vst[c * 8 + n] = Vin[b * 1024 + i];
    }
    if (t < 128) WVs[t] = WVin[b * 128 + t];
    if (t < 8) c0s[t] = c0in[b * 8 + t];
    if (t < 16) {
        float iv = lag[t] * rsqrtf(lav[t] + 1e-5f);
        inv1[t] = iv; bet1[t] = lab[t] - lam[t] * iv;
    }
    const u16* xb = xr + (size_t)b * 128 * HW + p0;
#pragma unroll
    for (int it = 0; it < 4; ++it) {
        int c = (t >> 3) + it * 32;
        int seg = t & 7;
        short8 v = *(const short8*)(xb + (size_t)c * HW + seg * 8);
        *(short8*)(&Xh[c * 64 + seg * 8]) = v;       // raw bf16 copy, b128 writes
    }
    __syncthreads();
    {
        int pp = t & 63, ng = t >> 6;
        float a0 = 0.f, a1 = 0.f;
        for (int c = 0; c < 128; ++c) {
            float x = bf2f(Xh[c * 64 + pp]);
            f32x2 av = *(const f32x2*)(&Ast[c * 8 + ng * 2]);   // 1 uniform b64
            a0 += av[0] * x;
            a1 += av[1] * x;
        }
        satt[(ng * 2) * 64 + pp] = a0 + c0s[ng * 2];
        satt[(ng * 2 + 1) * 64 + pp] = a1 + c0s[ng * 2 + 1];
    }
    __syncthreads();
    if (t < 64) {
        float m = -1e30f;
        float sv[8];
#pragma unroll
        for (int n = 0; n < 8; ++n) { sv[n] = satt[n * 64 + t]; m = fmaxf(m, sv[n]); }
        float sum = 0.f;
#pragma unroll
        for (int n = 0; n < 8; ++n) { sv[n] = __expf(sv[n] - m); sum += sv[n]; }
        float rcp = 1.f / sum;
#pragma unroll
        for (int n = 0; n < 8; ++n) satt[n * 64 + t] = sv[n] * rcp;
    }
    __syncthreads();
    {
        int pp = t & 63, cg = t >> 6;
        float at[8];
#pragma unroll
        for (int n = 0; n < 8; ++n) at[n] = satt[n * 64 + pp];
        // ctx -> global only (no LDS round-trip)
        for (int ci = 0; ci < 32; ++ci) {
            int c = cg * 32 + ci;
            f32x4 v0 = *(const f32x4*)(&Vst[c * 8]);       // 2 uniform b128
            f32x4 v1 = *(const f32x4*)(&Vst[c * 8 + 4]);
            float s = at[0] * v0[0] + at[1] * v0[1] + at[2] * v0[2] + at[3] * v0[3]
                    + at[4] * v1[0] + at[5] * v1[1] + at[6] * v1[2] + at[7] * v1[3];
            ctxout[((size_t)b * 128 + c) * HW + p0 + pp] = s;   // fp32
        }
        // y = WV @ att : 8 FMA per output d (cg doubles as dg, same pp)
        float a[4] = {0.f, 0.f, 0.f, 0.f};
#pragma unroll
        for (int n = 0; n < 8; ++n) {
            f32x4 wv = *(const f32x4*)(&WVs[n * 16 + cg * 4]);  // uniform b128
#pragma unroll
            for (int k = 0; k < 4; ++k) a[k] += at[n] * wv[k];
        }
        s16x4 pk;
#pragma unroll
        for (int k = 0; k < 4; ++k) {
            int d = cg * 4 + k;
            float val = a[k] * inv1[d] + bet1[d];
            float s = val / (1.f + __expf(-val));
            pk[k] = (short)f2bf(s);
        }
        // y in NHWC-16: yt[b][p][d]
        *(s16x4*)(yout + ((size_t)b * HW + p0 + pp) * 16 + cg * 4) = pk;
    }
}

// ---------------------------------------------------------------------------
extern "C" void kernel_launch(void* const* d_in, const int* in_sizes, int n_in,
                              void* d_out, int out_size, void* d_ws, size_t ws_size,
                              hipStream_t stream)
{
    const float* x    = (const float*)d_in[0];
    const float* wred = (const float*)d_in[1];
    const float* bng  = (const float*)d_in[2];
    const float* bnb  = (const float*)d_in[3];
    const float* bnm  = (const float*)d_in[4];
    const float* bnv  = (const float*)d_in[5];
    const float* wq   = (const float*)d_in[6];
    const float* bq   = (const float*)d_in[7];
    const float* wk   = (const float*)d_in[8];
    const float* bk   = (const float*)d_in[9];
    const float* wv   = (const float*)d_in[10];
    const float* bv   = (const float*)d_in[11];
    // d_in[12] = lsh: provably unused (permutation-invariance of softmax attention)
    const float* wla1 = (const float*)d_in[13];
    const float* lag  = (const float*)d_in[14];
    const float* lab  = (const float*)d_in[15];
    const float* lam  = (const float*)d_in[16];
    const float* lav  = (const float*)d_in[17];
    const float* wla2 = (const float*)d_in[18];

    char* ws = (char*)d_ws;
    u16*   xr  = (u16*)(ws + 0);            // 18,874,368 B  bf16 CHW
    u16*   yt  = (u16*)(ws + 18874368);     //  2,359,296 B  bf16 NHWC-16
    u16*   Wt1 = (u16*)(ws + 21233664);     //    589,824 B
    u16*   Wt2 = (u16*)(ws + 21823488);     //     40,960 B
    float* Ab  = (float*)(ws + 21864448);   //     32,768 B
    float* Vb  = (float*)(ws + 21897216);   //     32,768 B
    float* c0b = (float*)(ws + 21929984);   //        256 B
    float* WVb = (float*)(ws + 21930240);   //      4,096 B  (8 b x 8 n x 16 d)
    // xt (NHWC-256 bf16, 37,748,736 B) lives in d_out until attn_k overwrites
    // it with fp32 ctx — conv1/prep complete before that (stream-ordered).
    u16*   xt   = (u16*)d_out;
    float* outp = (float*)d_out;
    // 16B zero region for conv halo lanes: Wt2's zero-padded tail (co=0,
    // k=144..151), written to 0 by transform_w each launch, 16B-aligned.
    const u16* zp = Wt2 + 144;

    transform_w<<<dim3(1232), dim3(256), 0, stream>>>(wred, wla2, Wt1, Wt2);

    transpose_x<<<dim3(1152), dim3(256), 0, stream>>>(x, xt);

    conv_k<256, 72, 2304, 1><<<dim3(768), dim3(256), 0, stream>>>(
        xt, Wt1, xr, nullptr, bng, bnb, bnm, bnv, nullptr, nullptr, zp);

    prep_attn<<<dim3(64), dim3(256), 0, stream>>>(
        xr, wk, bk, wv, bv, wq, bq, wla1, Ab, Vb, c0b, WVb);

    attn_k<<<dim3(1152), dim3(256), 0, stream>>>(
        xr, Ab, Vb, c0b, WVb, lag, lab, lam, lav, outp, yt);

    conv_k<16, 5, 160, 2><<<dim3(768), dim3(256), 0, stream>>>(
        yt, Wt2, nullptr, outp, nullptr, nullptr, nullptr, nullptr, xr, outp, zp);
}

// Round 11
// 276.125 us; speedup vs baseline: 1.0485x; 1.0112x over previous
//
#include <hip/hip_runtime.h>
#include <hip/hip_bf16.h>
#include <cmath>

typedef __attribute__((ext_vector_type(8))) short short8;
typedef __attribute__((ext_vector_type(16))) short short16;
typedef __attribute__((ext_vector_type(4))) short s16x4;
typedef __attribute__((ext_vector_type(4))) float f32x4;
typedef __attribute__((ext_vector_type(2))) float f32x2;
typedef unsigned short u16;

#define HW 9216   // 96*96

__device__ inline float bf2f(u16 u) {
    union { unsigned int i; float f; } x; x.i = ((unsigned int)u) << 16; return x.f;
}
__device__ inline u16 f2bf(float f) {
    union { unsigned int i; float f; } x; x.f = f;
    unsigned int r = x.i + 0x7FFF + ((x.i >> 16) & 1);
    return (u16)(r >> 16);
}

// Direct global->LDS DMA, 16 B per lane. LDS dest = wave-uniform base + lane*16;
// global src is per-lane (carries the gather/zero-fill redirect).
__device__ inline void gload16(const u16* g, u16* l) {
    __builtin_amdgcn_global_load_lds(
        (const __attribute__((address_space(1))) void*)g,
        (__attribute__((address_space(3))) void*)l,
        16, 0, 0);
}

#define VWAIT4 asm volatile("s_waitcnt vmcnt(4)" ::: "memory")
#define VWAIT3 asm volatile("s_waitcnt vmcnt(3)" ::: "memory")
#define VWAIT0 asm volatile("s_waitcnt vmcnt(0)" ::: "memory")

// ---------------------------------------------------------------------------
// MERGED pre-pass: [0,2304) = x transpose (CHW fp32 -> NHWC bf16, 32-px tiles,
// 9 blocks/CU, no occupancy tail); [2304,3536) = weight transform:
//   w_red [128,256,3,3] -> Wt1 [128][2304], k = c*288 + khw*32 + ciL
//   w_la2 [128,16,3,3]  -> Wt2 [128][160],  k = khw*16 + ci, zero pad 144..159
//   (Wt2's zero tail doubles as the 16B zero-page for conv halo lanes.)
// ---------------------------------------------------------------------------
__global__ __launch_bounds__(256) void prex_k(
    const float* __restrict__ X, u16* __restrict__ Xt,
    const float* __restrict__ wred, const float* __restrict__ wla2,
    u16* __restrict__ Wt1, u16* __restrict__ Wt2)
{
    __shared__ u16 Lt[256 * 35];      // [c][p], odd stride for bank spread
    int t = threadIdx.x;
    int bid = blockIdx.x;
    if (bid < 2304) {
        int b = bid & 7;
        int p0 = (bid >> 3) * 32;            // 288 chunks of 32 px
        int pp = t & 31, cg = t >> 5;        // cg 0..7
        const float* xb = X + (size_t)b * 256 * HW + p0 + pp;
        for (int r = 0; r < 32; ++r) {
            int c = r * 8 + cg;
            Lt[c * 35 + pp] = f2bf(xb[(size_t)c * HW]);
        }
        __syncthreads();
        int p = t >> 3, cq = t & 7;          // 8 lanes cover one 512B px row
        u16* ot = Xt + ((size_t)b * HW + p0 + p) * 256 + cq * 32;
#pragma unroll
        for (int o = 0; o < 2; ++o) {
            short16 v;
#pragma unroll
            for (int j = 0; j < 16; ++j)
                v[j] = (short)Lt[(cq * 32 + o * 16 + j) * 35 + p];
            *(short16*)(ot + o * 16) = v;    // 32B store; 8 lanes = contiguous 512B
        }
    } else {
        int idx = (bid - 2304) * 256 + t;
        if (idx < 128 * 2304) {
            int co = idx / 2304;
            int rem = idx - co * 2304;
            int c = rem / 288;
            int r2 = rem - c * 288;
            int khw = r2 >> 5, ciL = r2 & 31;
            Wt1[idx] = f2bf(wred[((co * 256 + c * 32 + ciL) * 9 + khw)]);
        } else {
            int i2 = idx - 128 * 2304;
            if (i2 < 128 * 160) {
                int co = i2 / 160;
                int k = i2 - co * 160;
                int khw = k >> 4, ci = k & 15;
                Wt2[i2] = (khw < 9) ? f2bf(wla2[((co << 4) + ci) * 9 + khw]) : (u16)0;
            }
        }
    }
}

// ---------------------------------------------------------------------------
// Implicit-GEMM 3x3 SAME conv via MFMA 16x16x32 bf16, NHWC bf16 input.
// R10: R4 staging (all via global_load_lds w16) + depth-2 counted-vmcnt:
// triple-buffered LDS, stage(kt+2)/iter, raw s_barrier preceded by COUNTED
// s_waitcnt vmcnt(C) so the newest batch stays in flight across the barrier
// (T4). NO sched_barrier(0) — R6's regression matched the m141 order-pinning
// failure; this isolates that variable. BN-const prep after the K-loop.
// C[co(128)][px(96=32w x 3h)]; grid 768 = 3 blocks/CU; LDS 43 KB.
// EPI==1: BN+SiLU -> bf16 OutH (xr).  EPI==2: out = xr + ctx*(1+tanh) -> fp32.
// ---------------------------------------------------------------------------
template<int CIN, int KTILES, int KP, int EPI>
__global__ __launch_bounds__(256) void conv_k(
    const u16* __restrict__ Xt, const u16* __restrict__ Wt,
    u16* OutH, float* OutF,
    const float* __restrict__ bg, const float* __restrict__ bb,
    const float* __restrict__ bm, const float* __restrict__ bv,
    const u16* __restrict__ xrb, const float* ctxf,
    const u16* __restrict__ zp)
{
    __shared__ __align__(16) short As[3][128 * 32];   // 24 KB
    __shared__ __align__(16) short Bs[3][96 * 32];    // 18 KB
    __shared__ float invA[128], betA[128];

    const int tid = threadIdx.x;
    const int bid = blockIdx.x;
    const int b = bid & 7;
    const int tile = bid >> 3;            // [0,96)
    const int w0 = (tile % 3) * 32;
    const int h0 = (tile / 3) * 3;        // 3-row tiles

    const int lane = tid & 63;
    const int wid = tid >> 6;
    const int wm = (wid & 1) * 64;   // m (co) offset of this wave
    const int wn = (wid >> 1) * 48;  // n (pixel) offset
    const int r = lane & 15;
    const int quad = lane >> 4;

    const u16* XtB = Xt + (size_t)b * HW * CIN;

    auto bsrc = [&](int slot, int kt) -> const u16* {
        int row = slot >> 2, o = slot & 3;
        int pw = row & 31, ph = row >> 5;        // 32w x 3h
        int hgl = h0 + ph, wgl = w0 + pw;
        if (CIN == 256) {
            int c = (kt * 57) >> 9;              // kt/9
            int khw = kt - c * 9;
            int dh = (khw * 11) >> 5;            // khw/3
            int dw = khw - 3 * dh;
            int hh = hgl + dh - 1, ww = wgl + dw - 1;
            bool ok = ((unsigned)hh < 96u) && ((unsigned)ww < 96u);
            return ok ? XtB + ((size_t)hh * 96 + ww) * 256 + c * 32 + o * 8 : zp;
        } else {
            int kg = kt * 32 + o * 8;
            int khw = kg >> 4, ci0 = kg & 15;
            int dh = (khw * 11) >> 5, dw = khw - 3 * dh;
            int hh = hgl + dh - 1, ww = wgl + dw - 1;
            bool ok = ((unsigned)hh < 96u) && ((unsigned)ww < 96u) && (khw < 9);
            return ok ? XtB + ((size_t)hh * 96 + ww) * 16 + ci0 : zp;
        }
    };

    // Per-thread VMEM per stage: 2 (A) + 1 (B) + 1 (B, wid<2) = 4 / 3 (wave-uniform).
    auto stage = [&](int kt, int buf) {
        int sA0 = tid, sA1 = tid + 256;
        gload16(Wt + (size_t)(sA0 >> 2) * KP + kt * 32 + (sA0 & 3) * 8,
                (u16*)&As[buf][(64 * wid) * 8]);
        gload16(Wt + (size_t)(sA1 >> 2) * KP + kt * 32 + (sA1 & 3) * 8,
                (u16*)&As[buf][(256 + 64 * wid) * 8]);
        gload16(bsrc(tid, kt), (u16*)&Bs[buf][(64 * wid) * 8]);
        if (wid < 2)
            gload16(bsrc(tid + 256, kt), (u16*)&Bs[buf][(256 + 64 * wid) * 8]);
    };

    f32x4 acc[4][3];
    f32x4 zz = {0.f, 0.f, 0.f, 0.f};
#pragma unroll
    for (int i = 0; i < 4; i++)
#pragma unroll
        for (int j = 0; j < 3; j++) acc[i][j] = zz;

    // prologue: batches 0,1 issued; wait batch0 (batch1 stays in flight)
    stage(0, 0);
    stage(1, 1);
    if (wid < 2) VWAIT4; else VWAIT3;
    __builtin_amdgcn_s_barrier();

    for (int kt = 0; kt < KTILES; ++kt) {
        int cur = kt % 3;
        if (kt + 2 < KTILES) stage(kt + 2, (kt + 2) % 3);
        short8 af[4], bfr[3];
#pragma unroll
        for (int i = 0; i < 4; i++)
            af[i] = *(const short8*)(&As[cur][(wm + i * 16 + r) * 32 + quad * 8]);
#pragma unroll
        for (int j = 0; j < 3; j++)
            bfr[j] = *(const short8*)(&Bs[cur][(wn + j * 16 + r) * 32 + quad * 8]);
        __builtin_amdgcn_s_setprio(1);
#pragma unroll
        for (int i = 0; i < 4; i++)
#pragma unroll
            for (int j = 0; j < 3; j++)
                acc[i][j] = __builtin_amdgcn_mfma_f32_16x16x32_bf16(af[i], bfr[j], acc[i][j], 0, 0, 0);
        __builtin_amdgcn_s_setprio(0);
        if (kt + 1 < KTILES) {
            if (kt + 2 < KTILES) { if (wid < 2) VWAIT4; else VWAIT3; }
            else VWAIT0;
            __builtin_amdgcn_s_barrier();
        }
    }

    if constexpr (EPI == 1) {
        if (tid < 128) {
            float iv = bg[tid] * rsqrtf(bv[tid] + 1e-5f);
            invA[tid] = iv;
            betA[tid] = bb[tid] - bm[tid] * iv;
        }
        __syncthreads();
    }

    // ---- epilogue (HW-verified decode): co = wm+i*16+quad*4+g ; pixel = wn+j*16+r
#pragma unroll
    for (int i = 0; i < 4; i++) {
#pragma unroll
        for (int j = 0; j < 3; j++) {
            int pl = wn + j * 16 + r;
            int w = w0 + (pl & 31), h = h0 + (pl >> 5);
#pragma unroll
            for (int g = 0; g < 4; ++g) {
                int co = wm + i * 16 + quad * 4 + g;
                float v = acc[i][j][g];
                size_t oidx = ((size_t)b * 128 + co) * HW + h * 96 + w;
                if constexpr (EPI == 1) {
                    float val = v * invA[co] + betA[co];
                    float sv = val / (1.f + __expf(-val));   // SiLU
                    OutH[oidx] = f2bf(sv);
                } else {
                    float xv = bf2f(xrb[oidx]);
                    float cv = ctxf[oidx];                   // fp32 ctx, same slot
                    float e = __expf(2.f * v);
                    float th = 1.f - 2.f / (e + 1.f);        // tanh
                    OutF[oidx] = xv + cv * (1.f + th);       // fp32 final output
                }
            }
        }
    }
}

// ---------------------------------------------------------------------------
// Per-(batch, token) prep: token = 16x16 mean of xr -> k -> V row, folded A row,
// c0, and WV row (WV = V @ W1^T, 8x16 per batch). Grid 64, 256 threads.
// ---------------------------------------------------------------------------
__global__ __launch_bounds__(256) void prep_attn(
    const u16* __restrict__ xr,
    const float* __restrict__ wk, const float* __restrict__ bk,
    const float* __restrict__ wv, const float* __restrict__ bv,
    const float* __restrict__ wq, const float* __restrict__ bq,
    const float* __restrict__ wla1,
    float* __restrict__ Aout, float* __restrict__ Vout, float* __restrict__ c0out,
    float* __restrict__ WVout)
{
    __shared__ float part[256];
    __shared__ float tok[128];
    __shared__ float ks[32];
    __shared__ float vs[128];
    int t = threadIdx.x;
    int bid = blockIdx.x;
    int b = bid & 7, n = bid >> 3;
    int c = t & 127, half = t >> 7;
    int i0 = (n < 6) ? 0 : 16;
    int j0 = ((n < 6) ? n : (n - 6)) * 16;
    const u16* xb = xr + (size_t)(b * 128 + c) * HW;

    float s = 0.f;
    for (int rr = 0; rr < 8; ++rr) {
        int row = i0 + half * 8 + rr;
        const u16* rp = xb + row * 96 + j0;
        short8 v0 = *(const short8*)rp;
        short8 v1 = *(const short8*)(rp + 8);
#pragma unroll
        for (int j = 0; j < 8; ++j) s += bf2f((u16)v0[j]) + bf2f((u16)v1[j]);
    }
    part[t] = s;
    __syncthreads();
    if (t < 128) tok[t] = (part[t] + part[t + 128]) * (1.f / 256.f);
    __syncthreads();
    if (t < 32) {
        float s2 = bk[t];
        for (int cc = 0; cc < 128; ++cc) s2 += wk[t * 128 + cc] * tok[cc];
        ks[t] = s2;
    }
    __syncthreads();
    if (t < 128) {
        float s3 = bv[c];
        for (int c2 = 0; c2 < 128; ++c2) s3 += wv[c * 128 + c2] * tok[c2];
        Vout[((size_t)b * 8 + n) * 128 + c] = s3;
        vs[c] = s3;
    } else {
        float s4 = 0.f;
        for (int d = 0; d < 32; ++d) s4 += wq[d * 128 + c] * ks[d];
        Aout[((size_t)b * 8 + n) * 128 + c] = s4;
    }
    if (t == 0) {
        float s5 = 0.f;
        for (int d = 0; d < 32; ++d) s5 += bq[d] * ks[d];
        c0out[b * 8 + n] = s5;
    }
    __syncthreads();
    if (t < 16) {
        float s6 = 0.f;
        for (int cc = 0; cc < 128; ++cc) s6 += vs[cc] * wla1[t * 128 + cc];
        WVout[((size_t)b * 8 + n) * 16 + t] = s6;
    }
}

// ---------------------------------------------------------------------------
// Fused attention + LocalAtten 1x1 branch. 64 px/block, grid 1152 1-D
// (b = bid&7). ctx -> fp32 d_out; y -> NHWC-16 bf16 (for conv2 staging).
// R10: Xh stored TRANSPOSED [px][c] (stride 136, 16B-aligned rows) so the
// per-c lane reads become 16 ds_read_b128 instead of 128 ds_read_u16.
// A/V in native [n][c] layout (direct-copy staging, uniform b128 reads
// vectorized over c). FP accumulation order per output unchanged.
// ---------------------------------------------------------------------------
__global__ __launch_bounds__(256) void attn_k(
    const u16* __restrict__ xr,
    const float* __restrict__ Ain, const float* __restrict__ Vin,
    const float* __restrict__ c0in, const float* __restrict__ WVin,
    const float* __restrict__ lag, const float* __restrict__ lab,
    const float* __restrict__ lam, const float* __restrict__ lav,
    float* __restrict__ ctxout, u16* __restrict__ yout)
{
    __shared__ __align__(16) u16 Xh[64 * 136];       // [px][c], 17.4 KB
    __shared__ __align__(16) float Ast[8 * 128];     // [n][c]
    __shared__ __align__(16) float Vst[8 * 128];     // [n][c]
    __shared__ float WVs[128];                       // [n*16+d]
    __shared__ float satt[8 * 64];
    __shared__ float c0s[8], inv1[16], bet1[16];

    int t = threadIdx.x;
    int bid = blockIdx.x;
    int b = bid & 7;
    int p0 = (bid >> 3) * 64;

    for (int i = t; i < 1024; i += 256) {
        Ast[i] = Ain[b * 1024 + i];      // [n][c] native
        Vst[i] = Vin[b * 1024 + i];
    }
    if (t < 128) WVs[t] = WVin[b * 128 + t];
    if (t < 8) c0s[t] = c0in[b * 8 + t];
    if (t < 16) {
        float iv = lag[t] * rsqrtf(lav[t] + 1e-5f);
        inv1[t] = iv; bet1[t] = lab[t] - lam[t] * iv;
    }
    const u16* xb = xr + (size_t)b * 128 * HW + p0;
#pragma unroll
    for (int it = 0; it < 4; ++it) {
        int c = (t >> 3) + it * 32;
        int seg = t & 7;
        short8 v = *(const short8*)(xb + (size_t)c * HW + seg * 8);
#pragma unroll
        for (int j = 0; j < 8; ++j)
            Xh[(seg * 8 + j) * 136 + c] = (u16)v[j];   // transpose scatter
    }
    __syncthreads();
    {
        int pp = t & 63, ng = t >> 6;
        const float* A0 = &Ast[(ng * 2) * 128];
        const float* A1 = &Ast[(ng * 2 + 1) * 128];
        const u16* xrow = &Xh[pp * 136];
        float a0 = 0.f, a1 = 0.f;
        for (int c8 = 0; c8 < 16; ++c8) {
            short8 xv = *(const short8*)(&xrow[c8 * 8]);
            f32x4 q00 = *(const f32x4*)(&A0[c8 * 8]);
            f32x4 q01 = *(const f32x4*)(&A0[c8 * 8 + 4]);
            f32x4 q10 = *(const f32x4*)(&A1[c8 * 8]);
            f32x4 q11 = *(const f32x4*)(&A1[c8 * 8 + 4]);
#pragma unroll
            for (int j = 0; j < 4; ++j) {
                float x = bf2f((u16)xv[j]);
                a0 += q00[j] * x; a1 += q10[j] * x;
            }
#pragma unroll
            for (int j = 0; j < 4; ++j) {
                float x = bf2f((u16)xv[j + 4]);
                a0 += q01[j] * x; a1 += q11[j] * x;
            }
        }
        satt[(ng * 2) * 64 + pp] = a0 + c0s[ng * 2];
        satt[(ng * 2 + 1) * 64 + pp] = a1 + c0s[ng * 2 + 1];
    }
    __syncthreads();
    if (t < 64) {
        float m = -1e30f;
        float sv[8];
#pragma unroll
        for (int n = 0; n < 8; ++n) { sv[n] = satt[n * 64 + t]; m = fmaxf(m, sv[n]); }
        float sum = 0.f;
#pragma unroll
        for (int n = 0; n < 8; ++n) { sv[n] = __expf(sv[n] - m); sum += sv[n]; }
        float rcp = 1.f / sum;
#pragma unroll
        for (int n = 0; n < 8; ++n) satt[n * 64 + t] = sv[n] * rcp;
    }
    __syncthreads();
    {
        int pp = t & 63, cg = t >> 6;
        float at[8];
#pragma unroll
        for (int n = 0; n < 8; ++n) at[n] = satt[n * 64 + pp];
        for (int c4 = 0; c4 < 8; ++c4) {
            int c = cg * 32 + c4 * 4;
            float s0 = 0.f, s1 = 0.f, s2 = 0.f, s3 = 0.f;
#pragma unroll
            for (int n = 0; n < 8; ++n) {
                f32x4 vv = *(const f32x4*)(&Vst[n * 128 + c]);  // uniform b128, 4 c
                s0 += at[n] * vv[0]; s1 += at[n] * vv[1];
                s2 += at[n] * vv[2]; s3 += at[n] * vv[3];
            }
            size_t obase = ((size_t)b * 128 + c) * HW + p0 + pp;
            ctxout[obase] = s0;
            ctxout[obase + HW] = s1;
            ctxout[obase + 2 * HW] = s2;
            ctxout[obase + 3 * HW] = s3;
        }
        // y = WV @ att : 8 FMA per output d (cg doubles as dg, same pp)
        float a[4] = {0.f, 0.f, 0.f, 0.f};
#pragma unroll
        for (int n = 0; n < 8; ++n) {
            f32x4 wv = *(const f32x4*)(&WVs[n * 16 + cg * 4]);  // uniform b128
#pragma unroll
            for (int k = 0; k < 4; ++k) a[k] += at[n] * wv[k];
        }
        s16x4 pk;
#pragma unroll
        for (int k = 0; k < 4; ++k) {
            int d = cg * 4 + k;
            float val = a[k] * inv1[d] + bet1[d];
            float s = val / (1.f + __expf(-val));
            pk[k] = (short)f2bf(s);
        }
        *(s16x4*)(yout + ((size_t)b * HW + p0 + pp) * 16 + cg * 4) = pk;
    }
}

// ---------------------------------------------------------------------------
extern "C" void kernel_launch(void* const* d_in, const int* in_sizes, int n_in,
                              void* d_out, int out_size, void* d_ws, size_t ws_size,
                              hipStream_t stream)
{
    const float* x    = (const float*)d_in[0];
    const float* wred = (const float*)d_in[1];
    const float* bng  = (const float*)d_in[2];
    const float* bnb  = (const float*)d_in[3];
    const float* bnm  = (const float*)d_in[4];
    const float* bnv  = (const float*)d_in[5];
    const float* wq   = (const float*)d_in[6];
    const float* bq   = (const float*)d_in[7];
    const float* wk   = (const float*)d_in[8];
    const float* bk   = (const float*)d_in[9];
    const float* wv   = (const float*)d_in[10];
    const float* bv   = (const float*)d_in[11];
    // d_in[12] = lsh: provably unused (permutation-invariance of softmax attention)
    const float* wla1 = (const float*)d_in[13];
    const float* lag  = (const float*)d_in[14];
    const float* lab  = (const float*)d_in[15];
    const float* lam  = (const float*)d_in[16];
    const float* lav  = (const float*)d_in[17];
    const float* wla2 = (const float*)d_in[18];

    char* ws = (char*)d_ws;
    u16*   xr  = (u16*)(ws + 0);            // 18,874,368 B  bf16 CHW
    u16*   yt  = (u16*)(ws + 18874368);     //  2,359,296 B  bf16 NHWC-16
    u16*   Wt1 = (u16*)(ws + 21233664);     //    589,824 B
    u16*   Wt2 = (u16*)(ws + 21823488);     //     40,960 B
    float* Ab  = (float*)(ws + 21864448);   //     32,768 B
    float* Vb  = (float*)(ws + 21897216);   //     32,768 B
    float* c0b = (float*)(ws + 21929984);   //        256 B
    float* WVb = (float*)(ws + 21930240);   //      4,096 B  (8 b x 8 n x 16 d)
    // xt (NHWC-256 bf16, 37,748,736 B) lives in d_out until attn_k overwrites
    // it with fp32 ctx — conv1/prep complete before that (stream-ordered).
    u16*   xt   = (u16*)d_out;
    float* outp = (float*)d_out;
    // 16B zero region for conv halo lanes: Wt2's zero-padded tail (co=0,
    // k=144..151), written to 0 by prex_k each launch, 16B-aligned.
    const u16* zp = Wt2 + 144;

    prex_k<<<dim3(3536), dim3(256), 0, stream>>>(x, xt, wred, wla2, Wt1, Wt2);

    conv_k<256, 72, 2304, 1><<<dim3(768), dim3(256), 0, stream>>>(
        xt, Wt1, xr, nullptr, bng, bnb, bnm, bnv, nullptr, nullptr, zp);

    prep_attn<<<dim3(64), dim3(256), 0, stream>>>(
        xr, wk, bk, wv, bv, wq, bq, wla1, Ab, Vb, c0b, WVb);

    attn_k<<<dim3(1152), dim3(256), 0, stream>>>(
        xr, Ab, Vb, c0b, WVb, lag, lab, lam, lav, outp, yt);

    conv_k<16, 5, 160, 2><<<dim3(768), dim3(256), 0, stream>>>(
        yt, Wt2, nullptr, outp, nullptr, nullptr, nullptr, nullptr, xr, outp, zp);
}